// Round 5
// baseline (245.181 us; speedup 1.0000x reference)
//
#include <hip/hip_runtime.h>

// NCC loss: per-batch global sums + masked count, then scalar combine.
// SHAPE (16,1,64,128,128): B=16 volumes of VOL=1048576 f32 elements.
// Round 5: explicit register double-buffer pipeline (prefetch distance 2),
// 1024 fully-resident blocks, so the dataflow itself forces ~8 loads in
// flight per wave (compiler demoted the Round-4 batched loads to VGPR=32).

#define NB   16
#define VOL  (64 * 128 * 128)     // 1048576 elems per batch
#define BPB  64                   // blocks per batch
#define TPB  256                  // threads per block
#define QPT  16                   // float4 quads per thread; BPB*TPB*QPT*4 == VOL
#define NBLK (NB * BPB)           // 1024 total blocks

__device__ __forceinline__ double wave_reduce(double v) {
    #pragma unroll
    for (int off = 32; off > 0; off >>= 1) v += __shfl_down(v, off, 64);
    return v;
}

// f32 threshold TH such that (f32 x < TH) <=> ((double)x < 0.247) exactly.
__device__ __forceinline__ float mask_thresh() {
    const float c = 0.247f;
    if ((double)c < 0.247) return __uint_as_float(__float_as_uint(c) + 1u);
    return c;
}

__global__ __launch_bounds__(TPB) void ncc_partial(
    const float* __restrict__ I, const float* __restrict__ J,
    const int* __restrict__ CI, const int* __restrict__ CJ,
    double* __restrict__ part)
{
    const int b   = blockIdx.y;
    const int tid = threadIdx.x;
    // quad index base: batch offset + block span + lane
    const size_t qbase = (size_t)b * (VOL / 4) + (size_t)blockIdx.x * (TPB * QPT) + tid;

    const float4* __restrict__ I4 = reinterpret_cast<const float4*>(I) + qbase;
    const float4* __restrict__ J4 = reinterpret_cast<const float4*>(J) + qbase;
    const int4*   __restrict__ C4 = reinterpret_cast<const int4*>(CI) + qbase;
    const int4*   __restrict__ D4 = reinterpret_cast<const int4*>(CJ) + qbase;

    const float TH = mask_thresh();
    float sI = 0.f, sJ = 0.f, sI2 = 0.f, sJ2 = 0.f, sIJ = 0.f;
    int cnt = 0;

    // ---- software pipeline, prefetch distance 2 ----
    float4 ibuf[2], jbuf[2];
    int4   cbuf[2], dbuf[2];
    ibuf[0] = I4[0];        jbuf[0] = J4[0];
    cbuf[0] = C4[0];        dbuf[0] = D4[0];
    ibuf[1] = I4[TPB];      jbuf[1] = J4[TPB];
    cbuf[1] = C4[TPB];      dbuf[1] = D4[TPB];

    #pragma unroll
    for (int i = 0; i < QPT; ++i) {
        const int cur = i & 1;                 // compile-time after unroll
        float4 iv = ibuf[cur];
        float4 jv = jbuf[cur];
        int4   cv = cbuf[cur];
        int4   dv = dbuf[cur];

        if (i + 2 < QPT) {                     // issue loads for iteration i+2
            ibuf[cur] = I4[(size_t)(i + 2) * TPB];
            jbuf[cur] = J4[(size_t)(i + 2) * TPB];
            cbuf[cur] = C4[(size_t)(i + 2) * TPB];
            dbuf[cur] = D4[(size_t)(i + 2) * TPB];
        }

        float fi[4] = {iv.x, iv.y, iv.z, iv.w};
        float fj[4] = {jv.x, jv.y, jv.z, jv.w};
        int   ki[4] = {cv.x, cv.y, cv.z, cv.w};
        int   kj[4] = {dv.x, dv.y, dv.z, dv.w};
        #pragma unroll
        for (int e = 0; e < 4; ++e) {
            sI += fi[e];
            sJ += fj[e];
            sI2 = fmaf(fi[e], fi[e], sI2);
            sJ2 = fmaf(fj[e], fj[e], sJ2);
            sIJ = fmaf(fi[e], fj[e], sIJ);
            bool zI = (fi[e] < TH) && (ki[e] > 0);
            bool zJ = (fj[e] < TH) && (kj[e] > 0);
            cnt += (!zI && !zJ) ? 1 : 0;
        }
    }

    double v[6] = {(double)sI, (double)sJ, (double)sI2,
                   (double)sJ2, (double)sIJ, (double)cnt};
    #pragma unroll
    for (int q = 0; q < 6; ++q) v[q] = wave_reduce(v[q]);

    __shared__ double sh[TPB / 64][6];
    const int wave = tid >> 6, lane = tid & 63;
    if (lane == 0) {
        #pragma unroll
        for (int q = 0; q < 6; ++q) sh[wave][q] = v[q];
    }
    __syncthreads();

    if (tid == 0) {
        const int gb = b * BPB + blockIdx.x;   // global block number
        #pragma unroll
        for (int q = 0; q < 6; ++q) {
            double o = 0.0;
            for (int w = 0; w < TPB / 64; ++w) o += sh[w][q];
            part[(size_t)q * NBLK + gb] = o;   // SoA: coalesced for final pass
        }
    }
}

__global__ __launch_bounds__(1024) void ncc_final(
    const double* __restrict__ part, float* __restrict__ outp)
{
    const int tid = threadIdx.x;
    const int w = tid >> 6;     // wave w <-> batch w (16 waves)
    const int l = tid & 63;

    // BPB=64 partials per batch: exactly one per lane
    double v[6];
    #pragma unroll
    for (int q = 0; q < 6; ++q) v[q] = part[(size_t)q * NBLK + w * BPB + l];
    #pragma unroll
    for (int q = 0; q < 6; ++q) v[q] = wave_reduce(v[q]);

    __shared__ double acc[NB];
    if (l == 0) {
        const double W = (double)VOL;
        double uI = v[0] / W, uJ = v[1] / W;
        double cross = v[4] - uJ * v[0] - uI * v[1] + uI * uJ * W;
        double Ivar  = v[2] - 2.0 * uI * v[0] + uI * uI * W;
        double Jvar  = v[3] - 2.0 * uJ * v[1] + uJ * uJ * W;
        double cc = (cross * cross) / (Ivar * Jvar + 1e-5);
        acc[w] = -cc * v[5];
    }
    __syncthreads();

    if (tid == 0) {
        double t = 0.0;
        for (int b = 0; b < NB; ++b) t += acc[b];
        outp[0] = (float)(t / ((double)NB * (double)VOL));
    }
}

extern "C" void kernel_launch(void* const* d_in, const int* in_sizes, int n_in,
                              void* d_out, int out_size, void* d_ws, size_t ws_size,
                              hipStream_t stream)
{
    const float* I  = (const float*)d_in[0];   // out
    const float* J  = (const float*)d_in[1];   // y_pred
    const int*   CI = (const int*)d_in[2];     // out_ccl
    const int*   CJ = (const int*)d_in[3];     // y_ccl
    double* part = (double*)d_ws;              // 6 * 1024 doubles = 48 KiB (SoA)

    dim3 grid(BPB, NB);
    ncc_partial<<<grid, TPB, 0, stream>>>(I, J, CI, CJ, part);
    ncc_final<<<1, 1024, 0, stream>>>(part, (float*)d_out);
}

// Round 6
// 242.905 us; speedup vs baseline: 1.0094x; 1.0094x over previous
//
#include <hip/hip_runtime.h>
#include <stdint.h>

// NCC loss, Round 6: wave-private LDS pipeline via global_load_lds.
// Register-destination loads kept getting demoted to ~2-in-flight (VGPR=32/36
// across 3 structurally different kernels). global_load_lds has NO VGPR
// destination, so in-flight depth is controlled by counted s_waitcnt vmcnt(N)
// (T3/T4 pattern), not by the register allocator. No __syncthreads anywhere:
// each wave owns a private 16KB LDS region -> no barrier drain.

#define NB    16
#define VOL   (64 * 128 * 128)     // 1048576 elems per batch
#define BPB   32                   // blocks per batch
#define TPB   256                  // 4 waves
#define NWV   4                    // waves per block
#define DEP   4                    // pipeline depth (stages in flight)
#define NST   32                   // stages per wave
#define NWP   (NB * BPB * NWV)     // 2048 wave-partial slots

static_assert((long long)BPB * NWV * NST * 64 * 4 == (long long)VOL, "coverage");

__device__ __forceinline__ double wave_reduce(double v) {
#pragma unroll
    for (int off = 32; off > 0; off >>= 1) v += __shfl_down(v, off, 64);
    return v;
}

// f32 threshold TH such that (f32 x < TH) <=> ((double)x < 0.247) exactly.
__device__ __forceinline__ float mask_thresh() {
    const float c = 0.247f;
    if ((double)c < 0.247) return __uint_as_float(__float_as_uint(c) + 1u);
    return c;
}

// 16B per lane, lds dest = wave-uniform base + lane*16 (HW rule).
__device__ __forceinline__ void gload_lds16(const void* g, void* l) {
    __builtin_amdgcn_global_load_lds(
        (const __attribute__((address_space(1))) void*)g,
        (__attribute__((address_space(3))) void*)l,
        16, 0, 0);
}

__global__ __launch_bounds__(TPB) void ncc_partial(
    const float* __restrict__ I, const float* __restrict__ J,
    const int* __restrict__ CI, const int* __restrict__ CJ,
    double* __restrict__ part)
{
    // [wave][slot][array][lane] : 4*4*4*64*16B = 64 KiB -> 2 blocks/CU
    __shared__ float4 stg[NWV][DEP][4][64];

    const int b = blockIdx.y, bx = blockIdx.x;
    const int tid = threadIdx.x, w = tid >> 6, l = tid & 63;

    // this wave's first quad index (quads = float4/int4 units)
    const size_t q0 = (size_t)b * (VOL / 4) + ((size_t)bx * NWV + w) * (NST * 64);

    const float4* gI = reinterpret_cast<const float4*>(I) + q0 + l;
    const float4* gJ = reinterpret_cast<const float4*>(J) + q0 + l;
    const int4*   gC = reinterpret_cast<const int4*>(CI) + q0 + l;
    const int4*   gD = reinterpret_cast<const int4*>(CJ) + q0 + l;

    // ---- prologue: fill DEP stages (16 loads in flight) ----
#pragma unroll
    for (int s = 0; s < DEP; ++s) {
        gload_lds16(gI + (size_t)s * 64, &stg[w][s][0][0]);
        gload_lds16(gJ + (size_t)s * 64, &stg[w][s][1][0]);
        gload_lds16(gC + (size_t)s * 64, &stg[w][s][2][0]);
        gload_lds16(gD + (size_t)s * 64, &stg[w][s][3][0]);
    }

    const float TH = mask_thresh();
    double aI = 0, aJ = 0, aI2 = 0, aJ2 = 0, aIJ = 0;
    int cnt = 0;

    auto consume = [&](int slot) {
        float4 iv = stg[w][slot][0][l];
        float4 jv = stg[w][slot][1][l];
        int4   cv = *reinterpret_cast<const int4*>(&stg[w][slot][2][l]);
        int4   dv = *reinterpret_cast<const int4*>(&stg[w][slot][3][l]);

        float pI  = (iv.x + iv.y) + (iv.z + iv.w);
        float pJ  = (jv.x + jv.y) + (jv.z + jv.w);
        float pI2 = fmaf(iv.x, iv.x, fmaf(iv.y, iv.y, fmaf(iv.z, iv.z, iv.w * iv.w)));
        float pJ2 = fmaf(jv.x, jv.x, fmaf(jv.y, jv.y, fmaf(jv.z, jv.z, jv.w * jv.w)));
        float pIJ = fmaf(iv.x, jv.x, fmaf(iv.y, jv.y, fmaf(iv.z, jv.z, iv.w * jv.w)));

        int pc = 0;
        {
            bool zI, zJ;
            zI = (iv.x < TH) && (cv.x > 0); zJ = (jv.x < TH) && (dv.x > 0); pc += (!zI && !zJ);
            zI = (iv.y < TH) && (cv.y > 0); zJ = (jv.y < TH) && (dv.y > 0); pc += (!zI && !zJ);
            zI = (iv.z < TH) && (cv.z > 0); zJ = (jv.z < TH) && (dv.z > 0); pc += (!zI && !zJ);
            zI = (iv.w < TH) && (cv.w > 0); zJ = (jv.w < TH) && (dv.w > 0); pc += (!zI && !zJ);
        }

        aI += (double)pI; aJ += (double)pJ;
        aI2 += (double)pI2; aJ2 += (double)pJ2; aIJ += (double)pIJ;
        cnt += pc;
    };

    // ---- steady state: wait stage t, consume, refill slot with stage t+DEP ----
#pragma unroll 4
    for (int t = 0; t < NST - DEP; ++t) {
        const int slot = t & (DEP - 1);
        // stages t+1..t+3 = 12 loads may stay outstanding; stage t is landed.
        asm volatile("s_waitcnt vmcnt(12)" ::: "memory");
        consume(slot);
        // WAR: slot's ds_reads must complete before the refill lands.
        asm volatile("s_waitcnt lgkmcnt(0)" ::: "memory");
        const size_t s2 = (size_t)(t + DEP) * 64;
        gload_lds16(gI + s2, &stg[w][slot][0][0]);
        gload_lds16(gJ + s2, &stg[w][slot][1][0]);
        gload_lds16(gC + s2, &stg[w][slot][2][0]);
        gload_lds16(gD + s2, &stg[w][slot][3][0]);
    }

    // ---- tail: drain and consume last DEP stages ----
    asm volatile("s_waitcnt vmcnt(0)" ::: "memory");
#pragma unroll
    for (int t = NST - DEP; t < NST; ++t) consume(t & (DEP - 1));

    double v[6] = {aI, aJ, aI2, aJ2, aIJ, (double)cnt};
#pragma unroll
    for (int q = 0; q < 6; ++q) v[q] = wave_reduce(v[q]);

    if (l == 0) {
        const int gw = (b * BPB + bx) * NWV + w;   // global wave id, batch-major
#pragma unroll
        for (int q = 0; q < 6; ++q) part[(size_t)q * NWP + gw] = v[q];
    }
}

__global__ __launch_bounds__(1024) void ncc_final(
    const double* __restrict__ part, float* __restrict__ outp)
{
    const int tid = threadIdx.x;
    const int w = tid >> 6;     // wave w <-> batch w (16 waves)
    const int l = tid & 63;

    // 128 wave-partials per batch: 2 per lane
    double v[6];
#pragma unroll
    for (int q = 0; q < 6; ++q) {
        const size_t base = (size_t)q * NWP + (size_t)w * (BPB * NWV);
        v[q] = part[base + l] + part[base + 64 + l];
    }
#pragma unroll
    for (int q = 0; q < 6; ++q) v[q] = wave_reduce(v[q]);

    __shared__ double acc[NB];
    if (l == 0) {
        const double W = (double)VOL;
        double uI = v[0] / W, uJ = v[1] / W;
        double cross = v[4] - uJ * v[0] - uI * v[1] + uI * uJ * W;
        double Ivar  = v[2] - 2.0 * uI * v[0] + uI * uI * W;
        double Jvar  = v[3] - 2.0 * uJ * v[1] + uJ * uJ * W;
        double cc = (cross * cross) / (Ivar * Jvar + 1e-5);
        acc[w] = -cc * v[5];
    }
    __syncthreads();

    if (tid == 0) {
        double t = 0.0;
        for (int b = 0; b < NB; ++b) t += acc[b];
        outp[0] = (float)(t / ((double)NB * (double)VOL));
    }
}

extern "C" void kernel_launch(void* const* d_in, const int* in_sizes, int n_in,
                              void* d_out, int out_size, void* d_ws, size_t ws_size,
                              hipStream_t stream)
{
    const float* I  = (const float*)d_in[0];   // out
    const float* J  = (const float*)d_in[1];   // y_pred
    const int*   CI = (const int*)d_in[2];     // out_ccl
    const int*   CJ = (const int*)d_in[3];     // y_ccl
    double* part = (double*)d_ws;              // 6 * 2048 doubles = 96 KiB (SoA)

    dim3 grid(BPB, NB);
    ncc_partial<<<grid, TPB, 0, stream>>>(I, J, CI, CJ, part);
    ncc_final<<<1, 1024, 0, stream>>>(part, (float*)d_out);
}